// Round 21
// baseline (57.679 us; speedup 1.0000x reference)
//
#include <hip/hip_runtime.h>
#include <hip/hip_bf16.h>

#define B_  512
#define T_  256
#define C_  384
#define H_  64
#define SCALE_ 0.05103103630798287f   // 384^-0.5

typedef float f32x4  __attribute__((ext_vector_type(4)));
typedef short bf16x8 __attribute__((ext_vector_type(8)));
typedef short bf16x4 __attribute__((ext_vector_type(4)));

__device__ __forceinline__ unsigned short f2bf(float f) {
    union { float f; unsigned u; } v; v.f = f;
    unsigned r = v.u + 0x7FFFu + ((v.u >> 16) & 1u);   // RNE
    return (unsigned short)(r >> 16);
}
__device__ __forceinline__ unsigned cvt_pk_bf16(float lo, float hi) {
    unsigned r;
    asm("v_cvt_pk_bf16_f32 %0, %1, %2" : "=v"(r) : "v"(lo), "v"(hi));
    return r;
}
// XOR-swizzled [R][64]-short tile index (row = 128 B = 8 x 16B blocks).
__device__ __forceinline__ int swz64(int row, int col) {
    return row * 64 + (((col >> 3) ^ (row & 7)) << 3) + (col & 7);
}

// Wave -> q-strip permutation: 4x4 magic square (rows AND cols sum to 30) ->
// phase-2 per-SIMD causal load balanced under either w%4 or w/4 SIMD mapping.
__constant__ int STRIP_MAP[16] = {0,14,13,3, 11,5,6,8, 7,9,10,4, 12,2,1,15};

// LDS (shorts): smem[73728] = 147456 B.  (R17/R20-verbatim layout)
//  Phase-1: wst[j] at j*12288, j=0..5 — all six W^T k=64 chunks resident.
//  Phase-2 (alias): Ks[0,16384) swz64 | Vt[16384,33280) | Pb[33280,53760)
//
// R21 = R20 + s_setprio(1) around MFMA clusters (T5): phase 1 and phase 2 are
// both barrier-free regions where waves drift -> scheduler can favor
// MFMA-issuing waves over load-issuing ones (the regime where setprio
// measured +4-7% on attention).
__global__ __launch_bounds__(1024, 4) void att_head_kernel(
    const float* __restrict__ x,  const float* __restrict__ Wk,
    const float* __restrict__ Wq, const float* __restrict__ Wv,
    float* __restrict__ out)
{
    __shared__ __align__(16) short smem[73728];
    short* const Ks = smem;              // alias (live after phase 1)
    short* const Vt = smem + 16384;
    short* const Pb = smem + 33280;

    const int tid  = threadIdx.x;
    const int b    = blockIdx.x;
    const int w    = tid >> 6;        // 0..15 (raw wave id: staging k-quad)
    const int lane = tid & 63;
    const int g    = lane >> 4;
    const int i    = lane & 15;
    const int sw   = STRIP_MAP[w];    // owned q-strip (phase 1 rows + phase 2)
    const int rb   = 16 * sw;

    const float* xb = x + (size_t)b * T_ * C_;
    const float* Wm[3] = { Wk, Wq, Wv };

    f32x4 accP[12];
    #pragma unroll
    for (int nb = 0; nb < 12; nb++) accP[nb] = f32x4{0.f, 0.f, 0.f, 0.f};

    // per-lane global base for this wave's A-rows
    const float* xrow = xb + (size_t)(rb + i) * C_ + g * 8;

    // ---- Stage ALL 6 W^T chunks (R17-verbatim; raw w = k-quad index) ----
    {
        float wfa[12], wfb[12];
        auto loadWchunk = [&](int j, float* dst) {
            #pragma unroll
            for (int m = 0; m < 3; m++) {
                const float* Wp = Wm[m] + (size_t)(j * 64 + w * 4) * H_ + lane;
                #pragma unroll
                for (int jj = 0; jj < 4; jj++) dst[m * 4 + jj] = Wp[jj * H_];
            }
        };
        auto writeWchunk = [&](int j, const float* src) {
            short* buf = smem + j * 12288;
            #pragma unroll
            for (int m = 0; m < 3; m++) {
                union { unsigned u; short s[2]; } p0, p1;
                p0.u = cvt_pk_bf16(src[4 * m + 0], src[4 * m + 1]);
                p1.u = cvt_pk_bf16(src[4 * m + 2], src[4 * m + 3]);
                bf16x4 pk;
                pk[0] = p0.s[0]; pk[1] = p0.s[1]; pk[2] = p1.s[0]; pk[3] = p1.s[1];
                const int row = m * 64 + lane;
                const int k0  = w * 4;
                *(bf16x4*)&buf[row * 64 + (((k0 >> 3) ^ (row & 7)) << 3) + (k0 & 7)] = pk;
            }
        };
        loadWchunk(0, wfa);
        #pragma unroll
        for (int j = 0; j < 6; j++) {
            float* curW = (j & 1) ? wfb : wfa;
            float* nxtW = (j & 1) ? wfa : wfb;
            if (j < 5) loadWchunk(j + 1, nxtW);   // issue next loads first (T14)
            writeWchunk(j, curW);
        }
    }
    // prefetch x chunk 0 (lands under the barrier wait)
    float4 xr[2][4];
    #pragma unroll
    for (int ks = 0; ks < 2; ks++)
        #pragma unroll
        for (int h = 0; h < 2; h++)
            xr[0][ks * 2 + h] = *(const float4*)(xrow + ks * 32 + h * 4);
    asm volatile("s_waitcnt lgkmcnt(0)\n\ts_barrier" ::: "memory");   // W^T resident

    // ---------------- Phase 1 (R17-verbatim + setprio): barrier-free ------------
    #pragma unroll
    for (int j = 0; j < 6; j++) {
        const int par = j & 1;
        const short* cur = smem + j * 12288;
        if (j < 5) {
            #pragma unroll
            for (int ks = 0; ks < 2; ks++)
                #pragma unroll
                for (int h = 0; h < 2; h++)
                    xr[par ^ 1][ks * 2 + h] = *(const float4*)(xrow + (j + 1) * 64 + ks * 32 + h * 4);
        }
        bf16x8 afs[2];
        #pragma unroll
        for (int ks = 0; ks < 2; ks++)
            #pragma unroll
            for (int h = 0; h < 2; h++) {
                const float4 v = xr[par][ks * 2 + h];
                afs[ks][h * 4 + 0] = (short)f2bf(v.x);
                afs[ks][h * 4 + 1] = (short)f2bf(v.y);
                afs[ks][h * 4 + 2] = (short)f2bf(v.z);
                afs[ks][h * 4 + 3] = (short)f2bf(v.w);
            }
        __builtin_amdgcn_s_setprio(1);
        #pragma unroll
        for (int nb = 0; nb < 12; nb++) {
            #pragma unroll
            for (int ks = 0; ks < 2; ks++) {
                const int brow = nb * 16 + i;
                const bf16x8 bfr = *(const bf16x8*)&cur[brow * 64 + (((ks * 4 + g) ^ (i & 7)) << 3)];
                accP[nb] = __builtin_amdgcn_mfma_f32_16x16x32_bf16(afs[ks], bfr, accP[nb], 0, 0, 0);
            }
        }
        __builtin_amdgcn_s_setprio(0);
    }
    // all waves must finish reading wst before K/Q/V overwrite it
    asm volatile("s_waitcnt lgkmcnt(0)\n\ts_barrier" ::: "memory");

    // ---------------- Epilogue (R20-verbatim, strip = sw) ----------------
    #pragma unroll
    for (int nb = 0; nb < 4; nb++)
        #pragma unroll
        for (int r = 0; r < 4; r++)
            Ks[swz64(rb + 4 * g + r, 16 * nb + i)] = (short)f2bf(accP[4 + nb][r]);
    asm volatile("s_waitcnt lgkmcnt(0)" ::: "memory");
    bf16x8 qf[2];
    #pragma unroll
    for (int ks = 0; ks < 2; ks++)
        qf[ks] = *(const bf16x8*)&Ks[(rb + i) * 64 + (((4 * ks + g) ^ (i & 7)) << 3)];
    asm volatile("s_waitcnt lgkmcnt(0)" ::: "memory");   // qf landed before overwrite
    #pragma unroll
    for (int nb = 0; nb < 4; nb++)
        #pragma unroll
        for (int r = 0; r < 4; r++)
            Ks[swz64(rb + 4 * g + r, 16 * nb + i)] = (short)f2bf(accP[nb][r]);
    #pragma unroll
    for (int nb = 0; nb < 4; nb++) {
        bf16x4 pk;
        #pragma unroll
        for (int r = 0; r < 4; r++) pk[r] = (short)f2bf(accP[8 + nb][r]);
        *(bf16x4*)&Vt[(16 * nb + i) * 264 + rb + 4 * g] = pk;
    }
    asm volatile("s_waitcnt lgkmcnt(0)\n\ts_barrier" ::: "memory");

    // ---------------- Phase 2 (R20-verbatim + setprio): online S^T --------------
    short* const myP = Pb + w * 1280;    // two [16][40] buffers (raw w: scratch slot)
    const float NEG_INF = -__builtin_inff();
    float mrun = NEG_INF, lrun = 0.f;
    f32x4 accO[4];
    #pragma unroll
    for (int ht = 0; ht < 4; ht++) accO[ht] = f32x4{0.f, 0.f, 0.f, 0.f};

    auto PVADD = [&](int bufsel, int ck) {
        const bf16x8 pf = *(const bf16x8*)&myP[bufsel * 640 + i * 40 + 8 * g];
        __builtin_amdgcn_s_setprio(1);
        #pragma unroll
        for (int ht = 0; ht < 4; ht++) {
            const bf16x8 vf = *(const bf16x8*)&Vt[(16 * ht + i) * 264 + 32 * ck + 8 * g];
            accO[ht] = __builtin_amdgcn_mfma_f32_16x16x32_bf16(vf, pf, accO[ht], 0, 0, 0);
        }
        __builtin_amdgcn_s_setprio(0);
    };

    const int npair = sw >> 1;           // last pair index; pair p = tiles 2p, 2p+1
    #pragma unroll
    for (int p = 0; p < 8; p++) {
        if (p <= npair) {                // wave-uniform
            // QK^T (S^T tiles): lane holds (kv = 16*(2p+s)+4g+r, q = rb+i)
            f32x4 sA[2];
            sA[0] = f32x4{0.f, 0.f, 0.f, 0.f};
            sA[1] = f32x4{0.f, 0.f, 0.f, 0.f};
            __builtin_amdgcn_s_setprio(1);
            #pragma unroll
            for (int s = 0; s < 2; s++) {
                const int nt = 2 * p + s;
                if (nt <= sw) {          // wave-uniform
                    #pragma unroll
                    for (int ks = 0; ks < 2; ks++) {
                        const bf16x8 kfr = *(const bf16x8*)&Ks[(16 * nt + i) * 64 +
                                (((4 * ks + g) ^ (i & 7)) << 3)];
                        sA[s] = __builtin_amdgcn_mfma_f32_16x16x32_bf16(kfr, qf[ks], sA[s], 0, 0, 0);
                    }
                }
            }
            __builtin_amdgcn_s_setprio(0);
            if (p > 0) PVADD((p - 1) & 1, p - 1);   // pipelined PV of prev pair

            float mt = NEG_INF;
            #pragma unroll
            for (int s = 0; s < 2; s++)
                #pragma unroll
                for (int r = 0; r < 4; r++) {
                    const int kv = 16 * (2 * p + s) + 4 * g + r;
                    const bool ok = (2 * p + s <= sw) && (kv <= rb + i);
                    const float v = ok ? sA[s][r] * SCALE_ : NEG_INF;
                    sA[s][r] = v;
                    mt = fmaxf(mt, v);
                }
            mt = fmaxf(mt, __shfl_xor(mt, 16, 64));
            mt = fmaxf(mt, __shfl_xor(mt, 32, 64));

            if (!__all(mt <= mrun + 8.0f)) {        // defer-max (THR=8)
                const float mnew = fmaxf(mrun, mt);
                const float f = __expf(mrun - mnew);
                mrun = mnew; lrun *= f;
                #pragma unroll
                for (int ht = 0; ht < 4; ht++)
                    #pragma unroll
                    for (int r = 0; r < 4; r++) accO[ht][r] *= f;
            }
            #pragma unroll
            for (int s = 0; s < 2; s++) {
                const float p0 = __expf(sA[s][0] - mrun);
                const float p1 = __expf(sA[s][1] - mrun);
                const float p2 = __expf(sA[s][2] - mrun);
                const float p3 = __expf(sA[s][3] - mrun);
                lrun += (p0 + p1) + (p2 + p3);
                union { bf16x4 v; unsigned u[2]; } pk;
                pk.u[0] = cvt_pk_bf16(p0, p1);
                pk.u[1] = cvt_pk_bf16(p2, p3);
                *(bf16x4*)&myP[(p & 1) * 640 + i * 40 + 16 * s + 4 * g] = pk.v;
            }
        }
    }
    PVADD(npair & 1, npair);             // drain last pair

    // final denominator (sum across the 4 g-lanes of column q)
    lrun += __shfl_xor(lrun, 16, 64);
    lrun += __shfl_xor(lrun, 32, 64);
    const float inv = 1.f / lrun;

    // store O^T: lane holds (h = 16ht+4g+r, q = rb+i) -> float4 per ht
    float* orow = out + ((size_t)b * T_ + rb + i) * H_;
    #pragma unroll
    for (int ht = 0; ht < 4; ht++) {
        float4 o;
        o.x = accO[ht][0] * inv;
        o.y = accO[ht][1] * inv;
        o.z = accO[ht][2] * inv;
        o.w = accO[ht][3] * inv;
        *(float4*)&orow[16 * ht + 4 * g] = o;
    }
}

extern "C" void kernel_launch(void* const* d_in, const int* in_sizes, int n_in,
                              void* d_out, int out_size, void* d_ws, size_t ws_size,
                              hipStream_t stream) {
    const float* x  = (const float*)d_in[0];
    const float* Wk = (const float*)d_in[1];
    const float* Wq = (const float*)d_in[2];
    const float* Wv = (const float*)d_in[3];
    float* out = (float*)d_out;
    (void)d_ws; (void)ws_size; (void)in_sizes; (void)n_in; (void)out_size;
    att_head_kernel<<<dim3(B_), dim3(1024), 0, stream>>>(x, Wk, Wq, Wv, out);
}

// Round 22
// 56.355 us; speedup vs baseline: 1.0235x; 1.0235x over previous
//
#include <hip/hip_runtime.h>
#include <hip/hip_bf16.h>

#define B_  512
#define T_  256
#define C_  384
#define H_  64
#define SCALE_ 0.05103103630798287f   // 384^-0.5

typedef float f32x4  __attribute__((ext_vector_type(4)));
typedef short bf16x8 __attribute__((ext_vector_type(8)));
typedef short bf16x4 __attribute__((ext_vector_type(4)));

__device__ __forceinline__ unsigned short f2bf(float f) {
    union { float f; unsigned u; } v; v.f = f;
    unsigned r = v.u + 0x7FFFu + ((v.u >> 16) & 1u);   // RNE
    return (unsigned short)(r >> 16);
}
__device__ __forceinline__ unsigned cvt_pk_bf16(float lo, float hi) {
    unsigned r;
    asm("v_cvt_pk_bf16_f32 %0, %1, %2" : "=v"(r) : "v"(lo), "v"(hi));
    return r;
}
// XOR-swizzled [R][64]-short tile index (row = 128 B = 8 x 16B blocks).
__device__ __forceinline__ int swz64(int row, int col) {
    return row * 64 + (((col >> 3) ^ (row & 7)) << 3) + (col & 7);
}

// Wave -> q-strip permutation: 4x4 magic square (rows AND cols sum to 30) ->
// phase-2 per-SIMD causal load balanced under either w%4 or w/4 SIMD mapping.
__constant__ int STRIP_MAP[16] = {0,14,13,3, 11,5,6,8, 7,9,10,4, 12,2,1,15};

// FINAL (R20, session best 56.5us; 2.53x over round-1 baseline).
// LDS (shorts): smem[73728] = 147456 B.
//  Phase-1: wst[j] at j*12288, j=0..5 — all six W^T k=64 chunks resident
//  (staged once, coalesced + software-pipelined). ONE barrier, then phase 1
//  runs barrier-free (read-only buffers; waves drift).
//  Phase-2 (alias): Ks[0,16384) swz64 | Vt[16384,33280) | Pb[33280,53760)
//
// Structural floor of the fused 1-WG/batch design: phase-1 LDS B-reads
// (16 waves x full W^T) ~27.6K cyc/WG dominate; sharing them requires
// >128 regs/wave (unified VGPR+AGPR pool at 4 waves/SIMD) — every sharing
// restructure spilled or exposed latency. 3 barriers total. Phase 2: online
// softmax in S^T orientation (mfma(K,Q)), defer-max (THR=8), double-buffered
// in-LDS P with PV pipelined one pair behind QK^T.
__global__ __launch_bounds__(1024, 4) void att_head_kernel(
    const float* __restrict__ x,  const float* __restrict__ Wk,
    const float* __restrict__ Wq, const float* __restrict__ Wv,
    float* __restrict__ out)
{
    __shared__ __align__(16) short smem[73728];
    short* const Ks = smem;              // alias (live after phase 1)
    short* const Vt = smem + 16384;
    short* const Pb = smem + 33280;

    const int tid  = threadIdx.x;
    const int b    = blockIdx.x;
    const int w    = tid >> 6;        // 0..15 (raw wave id: staging k-quad)
    const int lane = tid & 63;
    const int g    = lane >> 4;
    const int i    = lane & 15;
    const int sw   = STRIP_MAP[w];    // owned q-strip (phase 1 rows + phase 2)
    const int rb   = 16 * sw;

    const float* xb = x + (size_t)b * T_ * C_;
    const float* Wm[3] = { Wk, Wq, Wv };

    f32x4 accP[12];
    #pragma unroll
    for (int nb = 0; nb < 12; nb++) accP[nb] = f32x4{0.f, 0.f, 0.f, 0.f};

    // per-lane global base for this wave's A-rows
    const float* xrow = xb + (size_t)(rb + i) * C_ + g * 8;

    // ---- Stage ALL 6 W^T chunks (coalesced reads; raw w = k-quad index) ----
    {
        float wfa[12], wfb[12];
        auto loadWchunk = [&](int j, float* dst) {
            #pragma unroll
            for (int m = 0; m < 3; m++) {
                const float* Wp = Wm[m] + (size_t)(j * 64 + w * 4) * H_ + lane;
                #pragma unroll
                for (int jj = 0; jj < 4; jj++) dst[m * 4 + jj] = Wp[jj * H_];
            }
        };
        auto writeWchunk = [&](int j, const float* src) {
            short* buf = smem + j * 12288;
            #pragma unroll
            for (int m = 0; m < 3; m++) {
                union { unsigned u; short s[2]; } p0, p1;
                p0.u = cvt_pk_bf16(src[4 * m + 0], src[4 * m + 1]);
                p1.u = cvt_pk_bf16(src[4 * m + 2], src[4 * m + 3]);
                bf16x4 pk;
                pk[0] = p0.s[0]; pk[1] = p0.s[1]; pk[2] = p1.s[0]; pk[3] = p1.s[1];
                const int row = m * 64 + lane;
                const int k0  = w * 4;
                *(bf16x4*)&buf[row * 64 + (((k0 >> 3) ^ (row & 7)) << 3) + (k0 & 7)] = pk;
            }
        };
        loadWchunk(0, wfa);
        #pragma unroll
        for (int j = 0; j < 6; j++) {
            float* curW = (j & 1) ? wfb : wfa;
            float* nxtW = (j & 1) ? wfa : wfb;
            if (j < 5) loadWchunk(j + 1, nxtW);   // issue next loads first (T14)
            writeWchunk(j, curW);
        }
    }
    // prefetch x chunk 0 (lands under the barrier wait)
    float4 xr[2][4];
    #pragma unroll
    for (int ks = 0; ks < 2; ks++)
        #pragma unroll
        for (int h = 0; h < 2; h++)
            xr[0][ks * 2 + h] = *(const float4*)(xrow + ks * 32 + h * 4);
    asm volatile("s_waitcnt lgkmcnt(0)\n\ts_barrier" ::: "memory");   // W^T resident

    // ---------------- Phase 1: 6 chunks of k=64, barrier-free ----------------
    #pragma unroll
    for (int j = 0; j < 6; j++) {
        const int par = j & 1;
        const short* cur = smem + j * 12288;
        if (j < 5) {
            #pragma unroll
            for (int ks = 0; ks < 2; ks++)
                #pragma unroll
                for (int h = 0; h < 2; h++)
                    xr[par ^ 1][ks * 2 + h] = *(const float4*)(xrow + (j + 1) * 64 + ks * 32 + h * 4);
        }
        bf16x8 afs[2];
        #pragma unroll
        for (int ks = 0; ks < 2; ks++)
            #pragma unroll
            for (int h = 0; h < 2; h++) {
                const float4 v = xr[par][ks * 2 + h];
                afs[ks][h * 4 + 0] = (short)f2bf(v.x);
                afs[ks][h * 4 + 1] = (short)f2bf(v.y);
                afs[ks][h * 4 + 2] = (short)f2bf(v.z);
                afs[ks][h * 4 + 3] = (short)f2bf(v.w);
            }
        #pragma unroll
        for (int nb = 0; nb < 12; nb++) {
            #pragma unroll
            for (int ks = 0; ks < 2; ks++) {
                const int brow = nb * 16 + i;
                const bf16x8 bfr = *(const bf16x8*)&cur[brow * 64 + (((ks * 4 + g) ^ (i & 7)) << 3)];
                accP[nb] = __builtin_amdgcn_mfma_f32_16x16x32_bf16(afs[ks], bfr, accP[nb], 0, 0, 0);
            }
        }
    }
    // all waves must finish reading wst before K/Q/V overwrite it
    asm volatile("s_waitcnt lgkmcnt(0)\n\ts_barrier" ::: "memory");

    // ---------------- Epilogue (strip = sw) ----------------
    // (1) Q -> own Ks slice (rows rb..rb+16), wave-local transpose
    #pragma unroll
    for (int nb = 0; nb < 4; nb++)
        #pragma unroll
        for (int r = 0; r < 4; r++)
            Ks[swz64(rb + 4 * g + r, 16 * nb + i)] = (short)f2bf(accP[4 + nb][r]);
    asm volatile("s_waitcnt lgkmcnt(0)" ::: "memory");
    bf16x8 qf[2];
    #pragma unroll
    for (int ks = 0; ks < 2; ks++)
        qf[ks] = *(const bf16x8*)&Ks[(rb + i) * 64 + (((4 * ks + g) ^ (i & 7)) << 3)];
    asm volatile("s_waitcnt lgkmcnt(0)" ::: "memory");   // qf landed before overwrite
    // (2) K -> same slice (b16 scatter)
    #pragma unroll
    for (int nb = 0; nb < 4; nb++)
        #pragma unroll
        for (int r = 0; r < 4; r++)
            Ks[swz64(rb + 4 * g + r, 16 * nb + i)] = (short)f2bf(accP[nb][r]);
    // (3) V -> Vt[h][t], packed b64 (r-consecutive t)
    #pragma unroll
    for (int nb = 0; nb < 4; nb++) {
        bf16x4 pk;
        #pragma unroll
        for (int r = 0; r < 4; r++) pk[r] = (short)f2bf(accP[8 + nb][r]);
        *(bf16x4*)&Vt[(16 * nb + i) * 264 + rb + 4 * g] = pk;
    }
    asm volatile("s_waitcnt lgkmcnt(0)\n\ts_barrier" ::: "memory");

    // ---------------- Phase 2: online causal attention, S^T orientation ---------
    short* const myP = Pb + w * 1280;    // two [16][40] buffers (raw w: scratch slot)
    const float NEG_INF = -__builtin_inff();
    float mrun = NEG_INF, lrun = 0.f;
    f32x4 accO[4];
    #pragma unroll
    for (int ht = 0; ht < 4; ht++) accO[ht] = f32x4{0.f, 0.f, 0.f, 0.f};

    auto PVADD = [&](int bufsel, int ck) {
        const bf16x8 pf = *(const bf16x8*)&myP[bufsel * 640 + i * 40 + 8 * g];
        #pragma unroll
        for (int ht = 0; ht < 4; ht++) {
            const bf16x8 vf = *(const bf16x8*)&Vt[(16 * ht + i) * 264 + 32 * ck + 8 * g];
            accO[ht] = __builtin_amdgcn_mfma_f32_16x16x32_bf16(vf, pf, accO[ht], 0, 0, 0);
        }
    };

    const int npair = sw >> 1;           // last pair index; pair p = tiles 2p, 2p+1
    #pragma unroll
    for (int p = 0; p < 8; p++) {
        if (p <= npair) {                // wave-uniform
            // QK^T (S^T tiles): lane holds (kv = 16*(2p+s)+4g+r, q = rb+i)
            f32x4 sA[2];
            sA[0] = f32x4{0.f, 0.f, 0.f, 0.f};
            sA[1] = f32x4{0.f, 0.f, 0.f, 0.f};
            #pragma unroll
            for (int s = 0; s < 2; s++) {
                const int nt = 2 * p + s;
                if (nt <= sw) {          // wave-uniform
                    #pragma unroll
                    for (int ks = 0; ks < 2; ks++) {
                        const bf16x8 kfr = *(const bf16x8*)&Ks[(16 * nt + i) * 64 +
                                (((4 * ks + g) ^ (i & 7)) << 3)];
                        sA[s] = __builtin_amdgcn_mfma_f32_16x16x32_bf16(kfr, qf[ks], sA[s], 0, 0, 0);
                    }
                }
            }
            if (p > 0) PVADD((p - 1) & 1, p - 1);   // pipelined PV of prev pair

            float mt = NEG_INF;
            #pragma unroll
            for (int s = 0; s < 2; s++)
                #pragma unroll
                for (int r = 0; r < 4; r++) {
                    const int kv = 16 * (2 * p + s) + 4 * g + r;
                    const bool ok = (2 * p + s <= sw) && (kv <= rb + i);
                    const float v = ok ? sA[s][r] * SCALE_ : NEG_INF;
                    sA[s][r] = v;
                    mt = fmaxf(mt, v);
                }
            mt = fmaxf(mt, __shfl_xor(mt, 16, 64));
            mt = fmaxf(mt, __shfl_xor(mt, 32, 64));

            if (!__all(mt <= mrun + 8.0f)) {        // defer-max (THR=8)
                const float mnew = fmaxf(mrun, mt);
                const float f = __expf(mrun - mnew);
                mrun = mnew; lrun *= f;
                #pragma unroll
                for (int ht = 0; ht < 4; ht++)
                    #pragma unroll
                    for (int r = 0; r < 4; r++) accO[ht][r] *= f;
            }
            #pragma unroll
            for (int s = 0; s < 2; s++) {
                const float p0 = __expf(sA[s][0] - mrun);
                const float p1 = __expf(sA[s][1] - mrun);
                const float p2 = __expf(sA[s][2] - mrun);
                const float p3 = __expf(sA[s][3] - mrun);
                lrun += (p0 + p1) + (p2 + p3);
                union { bf16x4 v; unsigned u[2]; } pk;
                pk.u[0] = cvt_pk_bf16(p0, p1);
                pk.u[1] = cvt_pk_bf16(p2, p3);
                *(bf16x4*)&myP[(p & 1) * 640 + i * 40 + 16 * s + 4 * g] = pk.v;
            }
        }
    }
    PVADD(npair & 1, npair);             // drain last pair

    // final denominator (sum across the 4 g-lanes of column q)
    lrun += __shfl_xor(lrun, 16, 64);
    lrun += __shfl_xor(lrun, 32, 64);
    const float inv = 1.f / lrun;

    // store O^T: lane holds (h = 16ht+4g+r, q = rb+i) -> float4 per ht
    float* orow = out + ((size_t)b * T_ + rb + i) * H_;
    #pragma unroll
    for (int ht = 0; ht < 4; ht++) {
        float4 o;
        o.x = accO[ht][0] * inv;
        o.y = accO[ht][1] * inv;
        o.z = accO[ht][2] * inv;
        o.w = accO[ht][3] * inv;
        *(float4*)&orow[16 * ht + 4 * g] = o;
    }
}

extern "C" void kernel_launch(void* const* d_in, const int* in_sizes, int n_in,
                              void* d_out, int out_size, void* d_ws, size_t ws_size,
                              hipStream_t stream) {
    const float* x  = (const float*)d_in[0];
    const float* Wk = (const float*)d_in[1];
    const float* Wq = (const float*)d_in[2];
    const float* Wv = (const float*)d_in[3];
    float* out = (float*)d_out;
    (void)d_ws; (void)ws_size; (void)in_sizes; (void)n_in; (void)out_size;
    att_head_kernel<<<dim3(B_), dim3(1024), 0, stream>>>(x, Wk, Wq, Wv, out);
}